// Round 2
// baseline (1169.568 us; speedup 1.0000x reference)
//
#include <hip/hip_runtime.h>
#include <hip/hip_bf16.h>
#include <math.h>

#define NRES 768
#define CS   384
#define CZ   128
#define CH   16
#define NH   12
#define PQK  4
#define PV   8
#define QCOLS   (NH*CH)        // 192
#define KVCOLS  (2*NH*CH)      // 384
#define QPCOLS  (NH*PQK*3)     // 144
#define KVPCOLS (NH*(PQK+PV)*3)// 432
#define CATC    (NH*(CZ+CH+PV*4)) // 2112
#define NN      (NRES*NRES)    // 589824

// ---------------- proj: tiled GEMM s(768x384) @ {Wq|Wkv|Wqp|Wkvp} ----------------
__global__ __launch_bounds__(256) void proj_kernel(
    const float* __restrict__ s,
    const float* __restrict__ Wq,  const float* __restrict__ bq,
    const float* __restrict__ Wkv, const float* __restrict__ bkv,
    const float* __restrict__ Wqp, const float* __restrict__ bqp,
    const float* __restrict__ Wkvp,const float* __restrict__ bkvp,
    float* __restrict__ proj_q, float* __restrict__ proj_kv,
    float* __restrict__ proj_qp, float* __restrict__ proj_kvp)
{
    __shared__ float Al[32][68];   // [k][m]
    __shared__ float Bl[32][52];   // [k][n]
    const int mt = blockIdx.x;     // 0..11
    const int gc0 = blockIdx.y * 48;
    const float* W; const float* bb; int ncol; float* dst; int c0;
    if (gc0 < 192)      { W=Wq;   bb=bq;   ncol=QCOLS;   dst=proj_q;   c0=gc0; }
    else if (gc0 < 576) { W=Wkv;  bb=bkv;  ncol=KVCOLS;  dst=proj_kv;  c0=gc0-192; }
    else if (gc0 < 720) { W=Wqp;  bb=bqp;  ncol=QPCOLS;  dst=proj_qp;  c0=gc0-576; }
    else                { W=Wkvp; bb=bkvp; ncol=KVPCOLS; dst=proj_kvp; c0=gc0-720; }
    const int tid = threadIdx.x;
    const int m0 = (tid & 15)*4;
    const int n0 = (tid >> 4)*3;
    float acc[4][3] = {};
    for (int kc = 0; kc < CS; kc += 32) {
        #pragma unroll
        for (int f = tid; f < 512; f += 256) {
            int r = f >> 3, c4 = (f & 7)*4;
            float4 v = *(const float4*)(s + (size_t)(mt*64+r)*CS + kc + c4);
            Al[c4][r]=v.x; Al[c4+1][r]=v.y; Al[c4+2][r]=v.z; Al[c4+3][r]=v.w;
        }
        for (int f = tid; f < 384; f += 256) {
            int r = f / 12, c4 = (f % 12)*4;
            *(float4*)&Bl[r][c4] = *(const float4*)(W + (size_t)(kc+r)*ncol + c0 + c4);
        }
        __syncthreads();
        #pragma unroll
        for (int kk = 0; kk < 32; ++kk) {
            float4 a = *(const float4*)&Al[kk][m0];
            float b0 = Bl[kk][n0], b1 = Bl[kk][n0+1], b2 = Bl[kk][n0+2];
            acc[0][0]+=a.x*b0; acc[0][1]+=a.x*b1; acc[0][2]+=a.x*b2;
            acc[1][0]+=a.y*b0; acc[1][1]+=a.y*b1; acc[1][2]+=a.y*b2;
            acc[2][0]+=a.z*b0; acc[2][1]+=a.z*b1; acc[2][2]+=a.z*b2;
            acc[3][0]+=a.w*b0; acc[3][1]+=a.w*b1; acc[3][2]+=a.w*b2;
        }
        __syncthreads();
    }
    #pragma unroll
    for (int r = 0; r < 4; ++r)
        #pragma unroll
        for (int c = 0; c < 3; ++c)
            dst[(size_t)(mt*64+m0+r)*ncol + c0+n0+c] = acc[r][c] + bb[c0+n0+c];
}

// ---------------- rotpts: points + packed layouts + out bias-init ----------------
// qfrag[q][h][28] = [16 q-chan | 12 q-pt comps]; kcat[h][28][768]; vcatT[h][40][768]
__global__ __launch_bounds__(256) void rotpts_kernel(
    const float* __restrict__ rot, const float* __restrict__ trans,
    const float* __restrict__ proj_q, const float* __restrict__ proj_kv,
    const float* __restrict__ proj_qp, const float* __restrict__ proj_kvp,
    const float* __restrict__ b_out,
    float* __restrict__ qfrag, float* __restrict__ kcat, float* __restrict__ vcatT,
    float* __restrict__ out)
{
    int g = blockIdx.x*256 + threadIdx.x;
    const int S0 = NRES*48;            // 36864  q points (n, h*4+p) -> 3 comps
    const int S1 = S0 + NRES*432;      // kv point comps, n fastest
    const int S2 = S1 + NRES*192;      // proj_q copy -> qfrag
    const int S3 = S2 + NRES*384;      // proj_kv copy -> kcat/vcatT, n fastest
    const int S4 = S3 + NRES*CS;       // out bias init
    if (g < S0) {
        int n = g/48, rem = g%48;
        int h = rem>>2, p = rem&3;
        float p0 = proj_qp[(size_t)n*QPCOLS + rem];
        float p1 = proj_qp[(size_t)n*QPCOLS + 48 + rem];
        float p2 = proj_qp[(size_t)n*QPCOLS + 96 + rem];
        const float* Rm = rot + (size_t)n*9; const float* t = trans + (size_t)n*3;
        float* dq = qfrag + ((size_t)n*12 + h)*28 + 16 + p*3;
        #pragma unroll
        for (int i = 0; i < 3; ++i)
            dq[i] = Rm[i*3]*p0 + Rm[i*3+1]*p1 + Rm[i*3+2]*p2 + t[i];
    } else if (g < S1) {
        int g2 = g - S0;
        int n = g2 % 768, t = g2 / 768;   // t in [0,432)
        int h = t/36, u = t%36, p = u/3, i = u%3;
        int col = h*12 + p;
        float p0 = proj_kvp[(size_t)n*KVPCOLS + col];
        float p1 = proj_kvp[(size_t)n*KVPCOLS + 144 + col];
        float p2 = proj_kvp[(size_t)n*KVPCOLS + 288 + col];
        float val = rot[(size_t)n*9 + i*3]*p0 + rot[(size_t)n*9 + i*3+1]*p1
                  + rot[(size_t)n*9 + i*3+2]*p2 + trans[(size_t)n*3 + i];
        if (p < PQK) kcat[(size_t)(h*28 + 16 + p*3 + i)*NRES + n] = val;
        else         vcatT[(size_t)(h*40 + 16 + (p-4)*3 + i)*NRES + n] = val;
    } else if (g < S2) {
        int g3 = g - S1;
        int n = g3 / 192, c = g3 % 192;
        int h = c >> 4, cc = c & 15;
        qfrag[((size_t)n*12 + h)*28 + cc] = proj_q[(size_t)n*QCOLS + c];
    } else if (g < S3) {
        int g4 = g - S2;
        int n = g4 % 768, col = g4 / 768;   // col in [0,384)
        int h = col >> 5, cc = col & 31;
        float val = proj_kv[(size_t)n*KVCOLS + col];
        if (cc < 16) kcat[(size_t)(h*28 + cc)*NRES + n] = val;
        else         vcatT[(size_t)(h*40 + (cc-16))*NRES + n] = val;
    } else if (g < S4) {
        int g5 = g - S3;
        out[g5] = b_out[g5 % CS];
    }
}

// ---------------- fused_attn: bias + logits + softmax + o/o_pt + o_pair per q ----------------
// One block per q. 512 threads = 8 waves, 3 blocks/CU (39.5 KB LDS).
// phase1: thread-per-k streams z[q,k,:] (bias matvec) + qk/pt logits vs kcat -> LDS
// phase2: wave-per-head softmax in LDS
// phase3: wave-per-row PV (o, o_pt-tilde), then (h,c4)-threads o_pair re-streaming z[q]
__global__ __launch_bounds__(512, 6) void fused_attn_kernel(
    const float* __restrict__ z, const float* __restrict__ mask,
    const float* __restrict__ W_b, const float* __restrict__ b_b,
    const float* __restrict__ qfrag, const float* __restrict__ kcat,
    const float* __restrict__ head_w, const float* __restrict__ vcatT,
    const float* __restrict__ rot, const float* __restrict__ trans,
    float* __restrict__ cat)
{
    __shared__ float lsm[12][768];     // logits -> probs (36 KB)
    __shared__ float qf_l[12][28];
    __shared__ float coef_l[12];
    __shared__ float optl[12][24];
    const int q = blockIdx.x;
    const int tid = threadIdx.x;
    for (int i = tid; i < 336; i += 512) qf_l[i/28][i - (i/28)*28] = qfrag[(size_t)q*336 + i];
    if (tid < 12) {
        float x = head_w[tid];
        float sp = (x > 20.f) ? x : log1pf(__expf(x));
        coef_l[tid] = -0.5f * sp * 0.13608276348795434f;   // sqrt(1/54)
    }
    __syncthreads();
    const float scale_qk = 0.14433756729740643f;  // sqrt(1/48)
    const float scale_b  = 0.5773502691896258f;   // sqrt(1/3)
    const float mq = mask[q];

    // ---- phase 1: logits for all (h,k) ----
    for (int k = tid; k < NRES; k += 512) {
        const float4* zr = (const float4*)(z + ((size_t)q*NRES + k)*CZ);
        float bacc[12] = {};
        #pragma unroll
        for (int c4 = 0; c4 < 32; ++c4) {
            float4 v = zr[c4];
            const float* w0 = W_b + c4*48;        // wave-uniform -> scalar loads
            #pragma unroll
            for (int h = 0; h < 12; ++h)
                bacc[h] += v.x*w0[h] + v.y*w0[12+h] + v.z*w0[24+h] + v.w*w0[36+h];
        }
        const float mterm = 100000.0f*(mq*mask[k] - 1.0f);
        #pragma unroll
        for (int h = 0; h < 12; ++h) {
            const float* kb = kcat + ((size_t)(h*28))*NRES + k;   // lane-coalesced (k fastest)
            float d = 0.f;
            #pragma unroll
            for (int c = 0; c < 16; ++c) d += qf_l[h][c]*kb[(size_t)c*NRES];
            float p2 = 0.f;
            #pragma unroll
            for (int c = 16; c < 28; ++c) { float t = qf_l[h][c] - kb[(size_t)c*NRES]; p2 += t*t; }
            lsm[h][k] = scale_qk*d + coef_l[h]*p2 + scale_b*(bacc[h] + b_b[h]) + mterm;
        }
    }
    __syncthreads();

    // ---- phase 2: softmax, wave per head row ----
    const int w = tid >> 6, ln = tid & 63;
    for (int h = w; h < 12; h += 8) {
        float* row = lsm[h];
        float vv[12]; float mx = -1e30f;
        #pragma unroll
        for (int j = 0; j < 12; ++j) { vv[j] = row[ln + j*64]; mx = fmaxf(mx, vv[j]); }
        #pragma unroll
        for (int o = 32; o > 0; o >>= 1) mx = fmaxf(mx, __shfl_xor(mx, o, 64));
        float s = 0.f;
        #pragma unroll
        for (int j = 0; j < 12; ++j) { vv[j] = __expf(vv[j]-mx); s += vv[j]; }
        #pragma unroll
        for (int o = 32; o > 0; o >>= 1) s += __shfl_xor(s, o, 64);
        float inv = 1.f/s;
        #pragma unroll
        for (int j = 0; j < 12; ++j) row[ln + j*64] = vv[j]*inv;
    }
    __syncthreads();

    float* crow = cat + (size_t)q*CATC;

    // ---- phase 3a: o (16 cols/h) + o_pt tilde (24 cols/h), wave-per-row ----
    for (int r = w; r < 480; r += 8) {
        const int h = r/40, col = r - (r/40)*40;
        const float* vrow = vcatT + (size_t)(h*40+col)*NRES;
        const float* ar = lsm[h];
        float p = 0.f;
        #pragma unroll
        for (int j = 0; j < 12; ++j) p += ar[ln + j*64]*vrow[ln + j*64];
        #pragma unroll
        for (int o = 32; o > 0; o >>= 1) p += __shfl_xor(p, o, 64);
        if (ln == 0) {
            if (col < 16) crow[h*16 + col] = p;
            else          optl[h][col-16] = p;
        }
    }
    __syncthreads();

    // ---- o_pt finalize: inverse rigid transform + norm (96 threads) ----
    if (tid < 96) {
        const int hh = tid >> 3, p = tid & 7;
        float b0 = optl[hh][p*3+0] - trans[q*3+0];
        float b1 = optl[hh][p*3+1] - trans[q*3+1];
        float b2 = optl[hh][p*3+2] - trans[q*3+2];
        const float* Rm = rot + (size_t)q*9;
        float v0 = Rm[0]*b0 + Rm[3]*b1 + Rm[6]*b2;
        float v1 = Rm[1]*b0 + Rm[4]*b1 + Rm[7]*b2;
        float v2 = Rm[2]*b0 + Rm[5]*b1 + Rm[8]*b2;
        crow[192 + tid] = v0;
        crow[288 + tid] = v1;
        crow[384 + tid] = v2;
        crow[480 + tid] = sqrtf(v0*v0 + v1*v1 + v2*v2 + 1e-8f);
    }

    // ---- phase 3b: o_pair, 384 threads (h, c4), re-stream z[q] (L3-hot) ----
    if (tid < 384) {
        const int h = tid >> 5, c4 = tid & 31;
        const float* zq = z + (size_t)q*NRES*CZ + c4*4;
        const float* ah = lsm[h];
        float4 acc = {0.f,0.f,0.f,0.f};
        for (int k = 0; k < NRES; k += 4) {
            float4 a4 = *(const float4*)(ah + k);          // broadcast within h-group
            float4 z0 = *(const float4*)(zq + (size_t)(k+0)*CZ);
            float4 z1 = *(const float4*)(zq + (size_t)(k+1)*CZ);
            float4 z2 = *(const float4*)(zq + (size_t)(k+2)*CZ);
            float4 z3 = *(const float4*)(zq + (size_t)(k+3)*CZ);
            acc.x += a4.x*z0.x + a4.y*z1.x + a4.z*z2.x + a4.w*z3.x;
            acc.y += a4.x*z0.y + a4.y*z1.y + a4.z*z2.y + a4.w*z3.y;
            acc.z += a4.x*z0.z + a4.y*z1.z + a4.z*z2.z + a4.w*z3.z;
            acc.w += a4.x*z0.w + a4.y*z1.w + a4.z*z2.w + a4.w*z3.w;
        }
        *(float4*)(crow + 576 + h*128 + c4*4) = acc;
    }
}

// ---------------- outgemm: 64x64 tile, 4x4 micro, split-K=6, atomicAdd ----------------
__global__ __launch_bounds__(256) void outgemm_kernel(
    const float* __restrict__ cat, const float* __restrict__ W_out,
    float* __restrict__ out)
{
    __shared__ float Al[32][68];   // [k][m]
    __shared__ float Bl[32][68];   // [k][n]
    const int mt = blockIdx.x;     // 0..11
    const int nt = blockIdx.y;     // 0..5
    const int kt = blockIdx.z;     // 0..5 (352 K each)
    const int tid = threadIdx.x;
    const int m0 = (tid & 15)*4, n0 = (tid >> 4)*4;
    float acc[4][4] = {};
    for (int ki = 0; ki < 11; ++ki) {
        int kc = kt*352 + ki*32;
        #pragma unroll
        for (int f = tid; f < 512; f += 256) {
            int r = f >> 3, c4 = (f & 7)*4;
            float4 v = *(const float4*)(cat + (size_t)(mt*64+r)*CATC + kc + c4);
            Al[c4][r]=v.x; Al[c4+1][r]=v.y; Al[c4+2][r]=v.z; Al[c4+3][r]=v.w;
        }
        #pragma unroll
        for (int f = tid; f < 512; f += 256) {
            int r = f >> 4, c4 = (f & 15)*4;
            *(float4*)&Bl[r][c4] = *(const float4*)(W_out + (size_t)(kc+r)*CS + nt*64 + c4);
        }
        __syncthreads();
        #pragma unroll
        for (int kk = 0; kk < 32; ++kk) {
            float4 a = *(const float4*)&Al[kk][m0];
            float4 b = *(const float4*)&Bl[kk][n0];
            acc[0][0]+=a.x*b.x; acc[0][1]+=a.x*b.y; acc[0][2]+=a.x*b.z; acc[0][3]+=a.x*b.w;
            acc[1][0]+=a.y*b.x; acc[1][1]+=a.y*b.y; acc[1][2]+=a.y*b.z; acc[1][3]+=a.y*b.w;
            acc[2][0]+=a.z*b.x; acc[2][1]+=a.z*b.y; acc[2][2]+=a.z*b.z; acc[2][3]+=a.z*b.w;
            acc[3][0]+=a.w*b.x; acc[3][1]+=a.w*b.y; acc[3][2]+=a.w*b.z; acc[3][3]+=a.w*b.w;
        }
        __syncthreads();
    }
    #pragma unroll
    for (int r = 0; r < 4; ++r)
        #pragma unroll
        for (int c = 0; c < 4; ++c)
            atomicAdd(&out[(size_t)(mt*64+m0+r)*CS + nt*64+n0+c], acc[r][c]);
}

extern "C" void kernel_launch(void* const* d_in, const int* in_sizes, int n_in,
                              void* d_out, int out_size, void* d_ws, size_t ws_size,
                              hipStream_t stream) {
    const float* s      = (const float*)d_in[0];
    const float* z      = (const float*)d_in[1];
    const float* rot    = (const float*)d_in[2];
    const float* trans  = (const float*)d_in[3];
    const float* mask   = (const float*)d_in[4];
    const float* W_q    = (const float*)d_in[5];
    const float* b_q    = (const float*)d_in[6];
    const float* W_kv   = (const float*)d_in[7];
    const float* b_kv   = (const float*)d_in[8];
    const float* W_qp   = (const float*)d_in[9];
    const float* b_qp   = (const float*)d_in[10];
    const float* W_kvp  = (const float*)d_in[11];
    const float* b_kvp  = (const float*)d_in[12];
    const float* W_b    = (const float*)d_in[13];
    const float* b_b    = (const float*)d_in[14];
    const float* head_w = (const float*)d_in[15];
    const float* W_out  = (const float*)d_in[16];
    const float* b_out  = (const float*)d_in[17];

    float* ws = (float*)d_ws;
    float* proj_q   = ws;                 // 147456
    float* proj_kv  = ws + 147456;        // 294912
    float* proj_qp  = ws + 442368;        // 110592
    float* proj_kvp = ws + 552960;        // 331776 (ends 884736)
    float* qfrag    = ws + 884736;        // 258048
    float* kcat     = ws + 1142784;       // 258048
    float* vcatT    = ws + 1400832;       // 368640
    float* cat      = ws + 1769472;       // 1622016 (total 3391488 floats = 13.6 MB)
    float* out = (float*)d_out;

    proj_kernel<<<dim3(12,24), 256, 0, stream>>>(s, W_q, b_q, W_kv, b_kv, W_qp, b_qp, W_kvp, b_kvp,
                                                 proj_q, proj_kv, proj_qp, proj_kvp);
    rotpts_kernel<<<4320, 256, 0, stream>>>(rot, trans, proj_q, proj_kv, proj_qp, proj_kvp, b_out,
                                            qfrag, kcat, vcatT, out);
    fused_attn_kernel<<<NRES, 512, 0, stream>>>(z, mask, W_b, b_b, qfrag, kcat, head_w, vcatT,
                                                rot, trans, cat);
    outgemm_kernel<<<dim3(12,6,6), 256, 0, stream>>>(cat, W_out, out);
}